// Round 10
// baseline (53.155 us; speedup 1.0000x reference)
//
#include <hip/hip_runtime.h>
#include <hip/hip_bf16.h>

typedef float f32x4 __attribute__((ext_vector_type(4)));
typedef __bf16 bf16x8 __attribute__((ext_vector_type(8)));

#define INF   8192             // in_features
#define FOLDS 127
#define LOCAL 128
#define OUTF  (FOLDS * LOCAL)  // 16256
#define BM    64               // batch rows per tile
#define BN    64               // output features per block (half a fold)
#define NT    8                // batch tiles per block (pipelined)
#define NBG   (2048 / (BM * NT))   // 4 batch groups

__device__ __forceinline__ void cvt_store8(char* lds, int byte, f32x4 v0, f32x4 v1) {
    bf16x8 w;
    w[0] = (__bf16)v0[0]; w[1] = (__bf16)v0[1]; w[2] = (__bf16)v0[2]; w[3] = (__bf16)v0[3];
    w[4] = (__bf16)v1[0]; w[5] = (__bf16)v1[1]; w[6] = (__bf16)v1[2]; w[7] = (__bf16)v1[3];
    *(bf16x8*)(lds + byte) = w;
}

// Ax: fp32 x tile, 64 rows x 512B, swizzle byte ^= (row&7)<<4 on 16B chunks
//     (staged by global_load_lds: linear LDS dest, inverse-swizzled SOURCE)
// Bs: bf16 W half-fold, 64 rows x 256B, same-family swizzle, staged once.
__global__ __launch_bounds__(256, 2)
void local_linear_kernel(const float* __restrict__ x,
                         const float* __restrict__ W,
                         const float* __restrict__ bias,
                         float* __restrict__ out)
{
    __shared__ __align__(16) float  Ax[2][BM * 128];   // 2 x 32 KiB
    __shared__ __align__(16) __bf16 Bs[BN * 128];      // 16 KiB

    const int bg  = blockIdx.x;          // batch group 0..3
    const int fn  = blockIdx.y;          // fold-half 0..253
    const int f   = fn >> 1;             // fold 0..126
    const int bn0 = (fn & 1) * BN;       // 0 or 64
    const int t   = threadIdx.x;         // 0..255

    const int lane = t & 63;
    const int wid  = t >> 6;
    const int wm   = wid >> 1;   // batch 32-block
    const int wn   = wid & 1;    // feature 32-block
    const int r16  = lane & 15;
    const int kq   = lane >> 4;  // 0..3

    const float* __restrict__ xf = x + (size_t)f * 64;

    // ---- x tile DMA: 8 x global_load_lds(16B) per thread, fire-and-forget ----
    auto stage_x = [&](int buf, int tile) {
        const size_t row0 = (size_t)(bg * NT + tile) * BM;
        char* dstbase = (char*)Ax[buf];
        #pragma unroll
        for (int c = 0; c < 8; ++c) {
            const int base = c * 4096 + wid * 1024;      // wave-uniform LDS byte base
            const int b    = base + lane * 16;           // this lane's linear dest
            const int row  = b >> 9;                     // batch row in tile
            const int srci = (b & 511) ^ ((row & 7) << 4);  // inverse swizzle on SOURCE
            const char* src = (const char*)(xf + (row0 + row) * INF) + srci;
            __builtin_amdgcn_global_load_lds(
                (const __attribute__((address_space(1))) void*)src,
                (__attribute__((address_space(3))) void*)(dstbase + base),
                16, 0, 0);
        }
    };

    stage_x(0, 0);   // tile-0 DMA flies while we stage W below

    // ---- stage W half-fold -> Bs (fp32 -> bf16, swizzled), once ----
    const float* __restrict__ Wf = W + (size_t)f * (LOCAL * 128) + (size_t)bn0 * 128;
    #pragma unroll
    for (int it = 0; it < 4; ++it) {
        const int e = it * 2048 + t * 8;
        const int row = e >> 7, col = e & 127;
        const float* g = Wf + row * 128 + col;
        f32x4 v0 = *(const f32x4*)g;
        f32x4 v1 = *(const f32x4*)(g + 4);
        cvt_store8((char*)Bs, (row * 256 + col * 2) ^ ((row & 7) << 4), v0, v1);
    }

    // bias (feature = n dim) — loaded before the sync so loop vmcnt counting stays exact
    float bv[2];
    #pragma unroll
    for (int j = 0; j < 2; ++j)
        bv[j] = bias[f * LOCAL + bn0 + wn * 32 + j * 16 + r16];

    __syncthreads();   // one-time full drain: Bs + tile-0 ready, vmcnt = 0

    // ---- pipelined main loop: per iter, counted vmcnt (never 0 mid-loop) ----
    // VMEM queue per thread, in issue order:
    //   iter tt: [L(tt+1) x8 staged at top] ... [S(tt) x16 stores mid-iter]
    // waits: tt==0 -> vmcnt(8) (trivial); 1..NT-2 -> vmcnt(24) = leave S(tt-1)16+L(tt+1)8;
    //        tt==NT-1 -> vmcnt(16) = leave S(NT-2)16, drain L(NT-1).
    #pragma unroll
    for (int tt = 0; tt < NT; ++tt) {
        if (tt + 1 < NT) {
            stage_x((tt + 1) & 1, tt + 1);
            if (tt == 0) asm volatile("s_waitcnt vmcnt(8)"  ::: "memory");
            else         asm volatile("s_waitcnt vmcnt(24)" ::: "memory");
        } else {
            asm volatile("s_waitcnt vmcnt(16)" ::: "memory");
        }
        __builtin_amdgcn_s_barrier();
        __builtin_amdgcn_sched_barrier(0);

        const int cb = tt & 1;
        f32x4 acc[2][2];
        #pragma unroll
        for (int i = 0; i < 2; ++i)
            #pragma unroll
            for (int j = 0; j < 2; ++j)
                acc[i][j] = (f32x4){bv[j], bv[j], bv[j], bv[j]};

        #pragma unroll
        for (int ks = 0; ks < 4; ++ks) {
            const int kof2 = ks * 128 + kq * 32;   // byte offset of this lane's 8 floats
            bf16x8 a[2], b[2];
            #pragma unroll
            for (int i = 0; i < 2; ++i) {
                const int row = wm * 32 + i * 16 + r16;
                const int sw  = (row & 7) << 4;
                const char* p = (const char*)Ax[cb] + row * 512;
                f32x4 u = *(const f32x4*)(p + ((kof2 +  0) ^ sw));
                f32x4 v = *(const f32x4*)(p + ((kof2 + 16) ^ sw));
                bf16x8 w;
                w[0] = (__bf16)u[0]; w[1] = (__bf16)u[1]; w[2] = (__bf16)u[2]; w[3] = (__bf16)u[3];
                w[4] = (__bf16)v[0]; w[5] = (__bf16)v[1]; w[6] = (__bf16)v[2]; w[7] = (__bf16)v[3];
                a[i] = w;
            }
            #pragma unroll
            for (int j = 0; j < 2; ++j) {
                const int row  = wn * 32 + j * 16 + r16;
                const int byte = (row * 256 + (ks * 32 + kq * 8) * 2) ^ ((row & 7) << 4);
                b[j] = *(const bf16x8*)((const char*)Bs + byte);
            }
            #pragma unroll
            for (int i = 0; i < 2; ++i)
                #pragma unroll
                for (int j = 0; j < 2; ++j)
                    acc[i][j] = __builtin_amdgcn_mfma_f32_16x16x32_bf16(a[i], b[j], acc[i][j], 0, 0, 0);
        }

        // ---- stores: exactly 16 global_store_dword per thread (counted) ----
        const int m0 = (bg * NT + tt) * BM;
        #pragma unroll
        for (int i = 0; i < 2; ++i) {
            const int mrow = m0 + wm * 32 + i * 16 + kq * 4;   // C/D: m = kq*4 + reg
            #pragma unroll
            for (int j = 0; j < 2; ++j) {
                const int ncol = f * LOCAL + bn0 + wn * 32 + j * 16 + r16;  // n = lane&15
                float* o = out + (size_t)mrow * OUTF + ncol;
                #pragma unroll
                for (int r = 0; r < 4; ++r)
                    o[(size_t)r * OUTF] = acc[i][j][r];
            }
        }

        __builtin_amdgcn_sched_barrier(0);
        __builtin_amdgcn_s_barrier();   // all waves done reading Ax[cb] before overwrite
    }
}

extern "C" void kernel_launch(void* const* d_in, const int* in_sizes, int n_in,
                              void* d_out, int out_size, void* d_ws, size_t ws_size,
                              hipStream_t stream) {
    const float* x    = (const float*)d_in[0];
    const float* W    = (const float*)d_in[1];
    const float* bias = (const float*)d_in[2];
    float* out        = (float*)d_out;

    dim3 grid(NBG, FOLDS * 2);   // 4 x 254 = 1016 blocks, 2 per CU
    dim3 block(256);
    local_linear_kernel<<<grid, block, 0, stream>>>(x, W, bias, out);
}

// Round 11
// 50.954 us; speedup vs baseline: 1.0432x; 1.0432x over previous
//
#include <hip/hip_runtime.h>
#include <hip/hip_bf16.h>

typedef float f32x4 __attribute__((ext_vector_type(4)));
typedef __bf16 bf16x8 __attribute__((ext_vector_type(8)));

#define INF   8192             // in_features
#define FOLDS 127
#define LOCAL 128
#define OUTF  (FOLDS * LOCAL)  // 16256
#define BM    64               // batch rows per block
#define BN    64               // output features per block (half a fold)

// As/Bs: 64 rows x 128 cols bf16 (row stride 256B), XOR swizzle byte ^= (row&7)<<4
__device__ __forceinline__ void cvt_store8(char* lds, int byte, f32x4 v0, f32x4 v1) {
    bf16x8 w;
    w[0] = (__bf16)v0[0]; w[1] = (__bf16)v0[1]; w[2] = (__bf16)v0[2]; w[3] = (__bf16)v0[3];
    w[4] = (__bf16)v1[0]; w[5] = (__bf16)v1[1]; w[6] = (__bf16)v1[2]; w[7] = (__bf16)v1[3];
    *(bf16x8*)(lds + byte) = w;
}

__global__ __launch_bounds__(256, 5)   // 32 KB LDS -> 5 blocks/CU, 20 waves/CU
void local_linear_kernel(const float* __restrict__ x,
                         const float* __restrict__ W,
                         const float* __restrict__ bias,
                         float* __restrict__ out)
{
    __shared__ __align__(16) __bf16 As[BM * 128];   // x tile, 16 KiB
    __shared__ __align__(16) __bf16 Bs[BN * 128];   // W half-fold, 16 KiB

    const int mt = blockIdx.x;          // batch tile 0..31
    const int fn = blockIdx.y;          // fold-half 0..253
    const int f  = fn >> 1;             // fold 0..126
    const int bn0 = (fn & 1) * BN;      // 0 or 64 within the fold's 128 outputs
    const int t  = threadIdx.x;         // 0..255

    const int m0   = mt * BM;
    const int lane = t & 63;
    const int wid  = t >> 6;
    const int wm   = wid >> 1;   // 0..1 (32 batch rows each)
    const int wn   = wid & 1;    // 0..1 (32 features each)
    const int r16  = lane & 15;
    const int kq   = lane >> 4;  // 0..3

    // ---- stage W half-fold -> Bs (fp32 -> bf16, swizzled): 64x128 ----
    const float* __restrict__ Wf = W + (size_t)f * (LOCAL * 128) + (size_t)bn0 * 128;
    #pragma unroll
    for (int it = 0; it < 4; ++it) {
        const int e   = it * 2048 + t * 8;
        const int row = e >> 7;        // l within half-fold (0..63)
        const int col = e & 127;       // k
        const float* g = Wf + row * 128 + col;
        f32x4 v0 = *(const f32x4*)g;
        f32x4 v1 = *(const f32x4*)(g + 4);
        cvt_store8((char*)Bs, (row * 256 + col * 2) ^ ((row & 7) << 4), v0, v1);
    }

    // ---- stage x tile -> As (fp32 -> bf16, swizzled): 64x128 ----
    const float* __restrict__ xg = x + (size_t)m0 * INF + (size_t)f * 64;
    #pragma unroll
    for (int it = 0; it < 4; ++it) {
        const int e   = it * 2048 + t * 8;
        const int row = e >> 7;        // batch row within tile (0..63)
        const int col = e & 127;       // k
        const float* g = xg + (size_t)row * INF + col;
        f32x4 v0 = *(const f32x4*)g;
        f32x4 v1 = *(const f32x4*)(g + 4);
        cvt_store8((char*)As, (row * 256 + col * 2) ^ ((row & 7) << 4), v0, v1);
    }
    __syncthreads();

    // ---- bias folded into accumulator init (bias depends on n only) ----
    float bv[2];
    #pragma unroll
    for (int j = 0; j < 2; ++j)
        bv[j] = bias[f * LOCAL + bn0 + wn * 32 + j * 16 + r16];

    f32x4 acc[2][2];
    #pragma unroll
    for (int i = 0; i < 2; ++i)
        #pragma unroll
        for (int j = 0; j < 2; ++j)
            acc[i][j] = (f32x4){bv[j], bv[j], bv[j], bv[j]};

    // ---- compute: 4 waves in 2x2, each 32x32 output; 4 MFMA per k-slice ----
    #pragma unroll
    for (int ks = 0; ks < 4; ++ks) {
        const int kof = ks * 32 + kq * 8;
        bf16x8 a[2], b[2];
        #pragma unroll
        for (int i = 0; i < 2; ++i) {
            const int row  = wm * 32 + i * 16 + r16;
            const int byte = (row * 256 + kof * 2) ^ ((row & 7) << 4);
            a[i] = *(const bf16x8*)((const char*)As + byte);
        }
        #pragma unroll
        for (int j = 0; j < 2; ++j) {
            const int row  = wn * 32 + j * 16 + r16;
            const int byte = (row * 256 + kof * 2) ^ ((row & 7) << 4);
            b[j] = *(const bf16x8*)((const char*)Bs + byte);
        }
        #pragma unroll
        for (int i = 0; i < 2; ++i)
            #pragma unroll
            for (int j = 0; j < 2; ++j)
                acc[i][j] = __builtin_amdgcn_mfma_f32_16x16x32_bf16(a[i], b[j], acc[i][j], 0, 0, 0);
    }

    // ---- epilogue: NON-TEMPORAL fp32 stores (write-once stream, keep L2 for reads) ----
    // C/D map: n = lane&15, m = (lane>>4)*4 + reg
    #pragma unroll
    for (int i = 0; i < 2; ++i) {
        const int mrow = m0 + wm * 32 + i * 16 + kq * 4;
        #pragma unroll
        for (int j = 0; j < 2; ++j) {
            const int ncol = f * LOCAL + bn0 + wn * 32 + j * 16 + r16;
            float* o = out + (size_t)mrow * OUTF + ncol;
            #pragma unroll
            for (int r = 0; r < 4; ++r)
                __builtin_nontemporal_store(acc[i][j][r], o + (size_t)r * OUTF);
        }
    }
}

extern "C" void kernel_launch(void* const* d_in, const int* in_sizes, int n_in,
                              void* d_out, int out_size, void* d_ws, size_t ws_size,
                              hipStream_t stream) {
    const float* x    = (const float*)d_in[0];
    const float* W    = (const float*)d_in[1];
    const float* bias = (const float*)d_in[2];
    float* out        = (float*)d_out;

    dim3 grid(2048 / BM, FOLDS * 2);   // 32 x 254 = 8128 blocks
    dim3 block(256);
    local_linear_kernel<<<grid, block, 0, stream>>>(x, W, bias, out);
}